// Round 4
// baseline (163.527 us; speedup 1.0000x reference)
//
#include <hip/hip_runtime.h>
#include <stdint.h>

#define OUT_HW     14
#define NBINS      196     // 14*14
#define C_TOTAL    256
#define C_PER_BLK  64
#define NBOXES     512
#define BUF_WORDS  2048    // 8 KB per buffer (double-buffered -> 16 KB)
#define MAX_STAGE  2       // ceil(512 chunks / 256 threads)

__device__ __forceinline__ void axis_entry(float coord, float L,
                                           int& lo, int& hi, float& wlo, float& whi) {
    // torchvision ROIAlign bilinear edge handling
    const bool valid = (coord >= -1.0f) && (coord <= L);
    const float c   = fminf(fmaxf(coord, 0.0f), L - 1.0f);
    const float flo = floorf(c);
    const float fhi = fminf(flo + 1.0f, L - 1.0f);
    whi = c - flo;
    wlo = 1.0f - whi;
    if (!valid) { wlo = 0.0f; whi = 0.0f; }
    lo = (int)flo;
    hi = (int)fhi;
}

__device__ __forceinline__ void load_lds16(const float* g, float* l) {
    __builtin_amdgcn_global_load_lds(
        (const __attribute__((address_space(1))) void*)g,
        (__attribute__((address_space(3))) void*)l, 16, 0, 0);
}

__global__ __launch_bounds__(256) void roi_pool_kernel(
    const float* __restrict__ x0, const float* __restrict__ x1,
    const float* __restrict__ x2, const float* __restrict__ x3,
    const float* __restrict__ boxes, float* __restrict__ out)
{
    __shared__ float tile[2][BUF_WORDS];

    const int m    = blockIdx.x;   // box
    const int cblk = blockIdx.y;   // 64-channel chunk
    const int tid  = threadIdx.x;

    // ---- block-uniform box/level setup ----
    const float bxi = boxes[m*5+0];
    const float bx0 = boxes[m*5+1];
    const float by0 = boxes[m*5+2];
    const float bx1 = boxes[m*5+3];
    const float by1 = boxes[m*5+4];

    const float sz = sqrtf((bx1 - bx0) * (by1 - by0));
    int lvl = (int)floorf(4.0f + log2f(sz * (1.0f/224.0f) + 1e-8f));
    lvl = min(max(lvl, 2), 5) - 2;

    const float scales[4] = {0.25f, 0.125f, 0.0625f, 0.03125f};
    const int   dims[4]   = {256, 128, 64, 32};
    const float scale = scales[lvl];
    const int   W  = dims[lvl];
    const int   HW = W * W;
    const float Lf = (float)W;
    const float* feat = (lvl == 0) ? x0 : (lvl == 1) ? x1 : (lvl == 2) ? x2 : x3;
    const int bidx = (int)bxi;

    const float rx0 = bx0*scale - 0.5f;
    const float ry0 = by0*scale - 0.5f;
    const float binw = (bx1*scale - 0.5f - rx0) * (1.0f/14.0f);
    const float binh = (by1*scale - 0.5f - ry0) * (1.0f/14.0f);

    // ---- footprint extents (samples are monotone) ----
    int ymin, ymax, xmin, xmax;
    {
        int lo, hi; float a, b;
        axis_entry(ry0 +  0.25f*binh, Lf, lo, hi, a, b); ymin = lo;
        axis_entry(ry0 + 13.75f*binh, Lf, lo, hi, a, b); ymax = hi;
        axis_entry(rx0 +  0.25f*binw, Lf, lo, hi, a, b); xmin = lo;
        axis_entry(rx0 + 13.75f*binw, Lf, lo, hi, a, b); xmax = hi;
    }
    const int x_start = xmin & ~3;                       // 16B-aligned window start
    int TW = (xmax - x_start + 1 + 15) & ~15;            // words per tile row (mult of 16)
    int NR = ymax - ymin + 1;                            // tile rows
    if (NR * TW > BUF_WORDS) NR = BUF_WORDS / TW;        // safety (unreachable for valid boxes)

    const int TWc    = TW >> 2;                          // 16B chunks per row
    const int swmask = ((TWc & 7) == 0) ? 7 : 3;         // row-XOR swizzle width (stays in-row)
    const int TC     = NR * TWc;                         // total chunks

    // ---- per-thread staging source offsets (constant across channels) ----
    int  goff[MAX_STAGE];
    bool gact[MAX_STAGE];
    #pragma unroll
    for (int s = 0; s < MAX_STAGE; ++s) {
        const int q  = tid + (s << 8);
        gact[s] = (q < TC);
        const int qq  = min(q, TC - 1);
        const int row = qq / TWc;
        const int cp  = qq - row * TWc;
        const int cc  = cp ^ (row & swmask);             // pre-swizzled global source
        int off = (ymin + row) * W + x_start + (cc << 2);
        off = min(off, HW - 4);                          // never read past the channel plane
        goff[s] = off;
    }

    // ---- per-thread tap setup (bin = thread) ----
    const bool active = (tid < NBINS);
    const int  t  = active ? tid : (NBINS - 1);
    const int  ph = t / OUT_HW;
    const int  pw = t - ph * OUT_HW;

    int yl0, yh0, yl1, yh1, xl0, xh0, xl1, xh1;
    float wy0, wy1, wy2, wy3, wx0, wx1, wx2, wx3;
    axis_entry(ry0 + ((float)ph + 0.25f)*binh, Lf, yl0, yh0, wy0, wy1);
    axis_entry(ry0 + ((float)ph + 0.75f)*binh, Lf, yl1, yh1, wy2, wy3);
    axis_entry(rx0 + ((float)pw + 0.25f)*binw, Lf, xl0, xh0, wx0, wx1);
    axis_entry(rx0 + ((float)pw + 0.75f)*binw, Lf, xl1, xh1, wx2, wx3);
    wy0 *= 0.25f; wy1 *= 0.25f; wy2 *= 0.25f; wy3 *= 0.25f;  // fold 2x2 mean

    const int sr[4] = { yl0 - ymin, yh0 - ymin, yl1 - ymin, yh1 - ymin };
    const int sc[4] = { xl0 - x_start, xh0 - x_start, xl1 - x_start, xh1 - x_start };

    int woff[16];
    #pragma unroll
    for (int i = 0; i < 4; ++i) {
        #pragma unroll
        for (int j = 0; j < 4; ++j) {
            const int r  = sr[i];
            const int c  = sc[j];
            const int cc = c >> 2;
            woff[i*4 + j] = r * TW + (((cc ^ (r & swmask)) << 2) | (c & 3));
        }
    }

    const float* fb = feat + ((size_t)bidx * C_TOTAL + (size_t)cblk * C_PER_BLK) * HW;
    float* ob = out + ((size_t)m * C_TOTAL + (size_t)cblk * C_PER_BLK) * NBINS + tid;

    // ---- prologue: stage channel 0 into buffer 0 ----
    #pragma unroll
    for (int s = 0; s < MAX_STAGE; ++s)
        if (gact[s]) load_lds16(fb + goff[s], &tile[0][(tid + (s << 8)) << 2]);

    // ---- channel loop: barrier (drains stage c) -> issue stage c+1 -> compute c ----
    #pragma unroll 2
    for (int c = 0; c < C_PER_BLK; ++c) {
        __syncthreads();   // vmcnt(0) drain: stage(c) resident; all waves done reading buf (c+1)&1
        if (c + 1 < C_PER_BLK) {
            const float* fc  = fb + (size_t)(c + 1) * HW;
            float*       dst = &tile[(c + 1) & 1][0];
            #pragma unroll
            for (int s = 0; s < MAX_STAGE; ++s)
                if (gact[s]) load_lds16(fc + goff[s], dst + ((tid + (s << 8)) << 2));
        }
        const float* bp = &tile[c & 1][0];
        const float v =
            wy0*(wx0*bp[woff[0]]  + wx1*bp[woff[1]]  + wx2*bp[woff[2]]  + wx3*bp[woff[3]])  +
            wy1*(wx0*bp[woff[4]]  + wx1*bp[woff[5]]  + wx2*bp[woff[6]]  + wx3*bp[woff[7]])  +
            wy2*(wx0*bp[woff[8]]  + wx1*bp[woff[9]]  + wx2*bp[woff[10]] + wx3*bp[woff[11]]) +
            wy3*(wx0*bp[woff[12]] + wx1*bp[woff[13]] + wx2*bp[woff[14]] + wx3*bp[woff[15]]);
        if (active) ob[(size_t)c * NBINS] = v;
    }
}

extern "C" void kernel_launch(void* const* d_in, const int* in_sizes, int n_in,
                              void* d_out, int out_size, void* d_ws, size_t ws_size,
                              hipStream_t stream) {
    const float* x0    = (const float*)d_in[0];
    const float* x1    = (const float*)d_in[1];
    const float* x2    = (const float*)d_in[2];
    const float* x3    = (const float*)d_in[3];
    const float* boxes = (const float*)d_in[4];
    float* out = (float*)d_out;

    dim3 grid(NBOXES, C_TOTAL / C_PER_BLK);
    dim3 block(256);
    roi_pool_kernel<<<grid, block, 0, stream>>>(x0, x1, x2, x3, boxes, out);
}

// Round 5
// 99.305 us; speedup vs baseline: 1.6467x; 1.6467x over previous
//
#include <hip/hip_runtime.h>
#include <stdint.h>

#define OUT_HW     14
#define NBINS      196     // 14*14
#define C_TOTAL    256
#define C_PER_BLK  64
#define C_PAIRS    (C_PER_BLK / 2)
#define NBOXES     512
#define BUF_WORDS  2048    // per-channel worst-case tile (8 KB)
#define MAX_STAGE  2       // ceil(512 chunks / 256 threads)

__device__ __forceinline__ void axis_entry(float coord, float L,
                                           int& lo, int& hi, float& wlo, float& whi) {
    // torchvision ROIAlign bilinear edge handling
    const bool valid = (coord >= -1.0f) && (coord <= L);
    const float c   = fminf(fmaxf(coord, 0.0f), L - 1.0f);
    const float flo = floorf(c);
    const float fhi = fminf(flo + 1.0f, L - 1.0f);
    whi = c - flo;
    wlo = 1.0f - whi;
    if (!valid) { wlo = 0.0f; whi = 0.0f; }
    lo = (int)flo;
    hi = (int)fhi;
}

__device__ __forceinline__ void load_lds16(const float* g, float* l) {
    __builtin_amdgcn_global_load_lds(
        (const __attribute__((address_space(1))) void*)g,
        (__attribute__((address_space(3))) void*)l, 16, 0, 0);
}

__global__ __launch_bounds__(256, 4) void roi_pool_kernel(
    const float* __restrict__ x0, const float* __restrict__ x1,
    const float* __restrict__ x2, const float* __restrict__ x3,
    const float* __restrict__ boxes, float* __restrict__ out)
{
    __shared__ float tile[2][2 * BUF_WORDS];   // 2 buffers x 2 channels x 8 KB = 32 KB

    const int m    = blockIdx.x;   // box
    const int cblk = blockIdx.y;   // 64-channel chunk
    const int tid  = threadIdx.x;

    // ---- block-uniform box/level setup ----
    const float bxi = boxes[m*5+0];
    const float bx0 = boxes[m*5+1];
    const float by0 = boxes[m*5+2];
    const float bx1 = boxes[m*5+3];
    const float by1 = boxes[m*5+4];

    const float sz = sqrtf((bx1 - bx0) * (by1 - by0));
    int lvl = (int)floorf(4.0f + log2f(sz * (1.0f/224.0f) + 1e-8f));
    lvl = min(max(lvl, 2), 5) - 2;

    const float scales[4] = {0.25f, 0.125f, 0.0625f, 0.03125f};
    const int   dims[4]   = {256, 128, 64, 32};
    const float scale = scales[lvl];
    const int   W  = dims[lvl];
    const int   HW = W * W;
    const float Lf = (float)W;
    const float* feat = (lvl == 0) ? x0 : (lvl == 1) ? x1 : (lvl == 2) ? x2 : x3;
    const int bidx = (int)bxi;

    const float rx0 = bx0*scale - 0.5f;
    const float ry0 = by0*scale - 0.5f;
    const float binw = (bx1*scale - 0.5f - rx0) * (1.0f/14.0f);
    const float binh = (by1*scale - 0.5f - ry0) * (1.0f/14.0f);

    // ---- footprint extents (samples are monotone) ----
    int ymin, ymax, xmin, xmax;
    {
        int lo, hi; float a, b;
        axis_entry(ry0 +  0.25f*binh, Lf, lo, hi, a, b); ymin = lo;
        axis_entry(ry0 + 13.75f*binh, Lf, lo, hi, a, b); ymax = hi;
        axis_entry(rx0 +  0.25f*binw, Lf, lo, hi, a, b); xmin = lo;
        axis_entry(rx0 + 13.75f*binw, Lf, lo, hi, a, b); xmax = hi;
    }
    const int x_start = xmin & ~3;                       // 16B-aligned window start
    int TW = (xmax - x_start + 1 + 15) & ~15;            // words per tile row (mult of 16)
    int NR = ymax - ymin + 1;                            // tile rows
    if (NR * TW > BUF_WORDS) NR = BUF_WORDS / TW;        // safety (unreachable for valid boxes)

    const int TWc    = TW >> 2;                          // 16B chunks per row
    const int swmask = ((TWc & 7) == 0) ? 7 : 3;         // row-XOR swizzle width (stays in-row)
    const int TC     = NR * TWc;                         // total chunks per channel

    // ---- per-thread staging source offsets (constant across channels) ----
    int  goff[MAX_STAGE];
    bool gact[MAX_STAGE];
    #pragma unroll
    for (int s = 0; s < MAX_STAGE; ++s) {
        const int q  = tid + (s << 8);
        gact[s] = (q < TC);
        const int qq  = min(q, TC - 1);
        const int row = qq / TWc;
        const int cp  = qq - row * TWc;
        const int cc  = cp ^ (row & swmask);             // pre-swizzled global source
        int off = (ymin + row) * W + x_start + (cc << 2);
        off = min(off, HW - 4);                          // never read past the channel plane
        goff[s] = off;
    }

    // ---- per-thread tap setup (bin = thread) ----
    const bool active = (tid < NBINS);
    const int  t  = active ? tid : (NBINS - 1);
    const int  ph = t / OUT_HW;
    const int  pw = t - ph * OUT_HW;

    int yl0, yh0, yl1, yh1, xl0, xh0, xl1, xh1;
    float wy0, wy1, wy2, wy3, wx0, wx1, wx2, wx3;
    axis_entry(ry0 + ((float)ph + 0.25f)*binh, Lf, yl0, yh0, wy0, wy1);
    axis_entry(ry0 + ((float)ph + 0.75f)*binh, Lf, yl1, yh1, wy2, wy3);
    axis_entry(rx0 + ((float)pw + 0.25f)*binw, Lf, xl0, xh0, wx0, wx1);
    axis_entry(rx0 + ((float)pw + 0.75f)*binw, Lf, xl1, xh1, wx2, wx3);
    wy0 *= 0.25f; wy1 *= 0.25f; wy2 *= 0.25f; wy3 *= 0.25f;  // fold 2x2 mean

    const int sr[4] = { yl0 - ymin, yh0 - ymin, yl1 - ymin, yh1 - ymin };
    const int sc[4] = { xl0 - x_start, xh0 - x_start, xl1 - x_start, xh1 - x_start };

    int woff[16];
    #pragma unroll
    for (int i = 0; i < 4; ++i) {
        #pragma unroll
        for (int j = 0; j < 4; ++j) {
            const int r  = sr[i];
            const int c  = sc[j];
            const int cc = c >> 2;
            woff[i*4 + j] = r * TW + (((cc ^ (r & swmask)) << 2) | (c & 3));
        }
    }

    const float* fb = feat + ((size_t)bidx * C_TOTAL + (size_t)cblk * C_PER_BLK) * HW;
    float* ob = out + ((size_t)m * C_TOTAL + (size_t)cblk * C_PER_BLK) * NBINS + tid;

    // ---- prologue: stage pair 0 (channels 0,1) into buffer 0 ----
    {
        const float* fc0 = fb;
        const float* fc1 = fb + HW;
        #pragma unroll
        for (int s = 0; s < MAX_STAGE; ++s) {
            if (gact[s]) {
                const int w = (tid + (s << 8)) << 2;
                load_lds16(fc0 + goff[s], &tile[0][w]);
                load_lds16(fc1 + goff[s], &tile[0][BUF_WORDS + w]);
            }
        }
    }

    // ---- pair loop: barrier (drains stage p) -> issue stage p+1 -> compute pair p ----
    for (int p = 0; p < C_PAIRS; ++p) {
        __syncthreads();   // vmcnt(0) drain: stage(p) resident; all waves done reading buf (p+1)&1
        if (p + 1 < C_PAIRS) {
            const float* fc0 = fb + (size_t)(2*p + 2) * HW;
            const float* fc1 = fb + (size_t)(2*p + 3) * HW;
            float*       dst = &tile[(p + 1) & 1][0];
            #pragma unroll
            for (int s = 0; s < MAX_STAGE; ++s) {
                if (gact[s]) {
                    const int w = (tid + (s << 8)) << 2;
                    load_lds16(fc0 + goff[s], dst + w);
                    load_lds16(fc1 + goff[s], dst + BUF_WORDS + w);
                }
            }
        }
        const float* b0 = &tile[p & 1][0];
        const float* b1 = &tile[p & 1][BUF_WORDS];
        const float v0 =
            wy0*(wx0*b0[woff[0]]  + wx1*b0[woff[1]]  + wx2*b0[woff[2]]  + wx3*b0[woff[3]])  +
            wy1*(wx0*b0[woff[4]]  + wx1*b0[woff[5]]  + wx2*b0[woff[6]]  + wx3*b0[woff[7]])  +
            wy2*(wx0*b0[woff[8]]  + wx1*b0[woff[9]]  + wx2*b0[woff[10]] + wx3*b0[woff[11]]) +
            wy3*(wx0*b0[woff[12]] + wx1*b0[woff[13]] + wx2*b0[woff[14]] + wx3*b0[woff[15]]);
        const float v1 =
            wy0*(wx0*b1[woff[0]]  + wx1*b1[woff[1]]  + wx2*b1[woff[2]]  + wx3*b1[woff[3]])  +
            wy1*(wx0*b1[woff[4]]  + wx1*b1[woff[5]]  + wx2*b1[woff[6]]  + wx3*b1[woff[7]])  +
            wy2*(wx0*b1[woff[8]]  + wx1*b1[woff[9]]  + wx2*b1[woff[10]] + wx3*b1[woff[11]]) +
            wy3*(wx0*b1[woff[12]] + wx1*b1[woff[13]] + wx2*b1[woff[14]] + wx3*b1[woff[15]]);
        if (active) {
            ob[(size_t)(2*p)     * NBINS] = v0;
            ob[(size_t)(2*p + 1) * NBINS] = v1;
        }
    }
}

extern "C" void kernel_launch(void* const* d_in, const int* in_sizes, int n_in,
                              void* d_out, int out_size, void* d_ws, size_t ws_size,
                              hipStream_t stream) {
    const float* x0    = (const float*)d_in[0];
    const float* x1    = (const float*)d_in[1];
    const float* x2    = (const float*)d_in[2];
    const float* x3    = (const float*)d_in[3];
    const float* boxes = (const float*)d_in[4];
    float* out = (float*)d_out;

    dim3 grid(NBOXES, C_TOTAL / C_PER_BLK);
    dim3 block(256);
    roi_pool_kernel<<<grid, block, 0, stream>>>(x0, x1, x2, x3, boxes, out);
}